// Round 8
// baseline (101.080 us; speedup 1.0000x reference)
//
#include <hip/hip_runtime.h>
#include <math.h>

#define TAU_F 0.02f
#define NB 64
#define NQ 32
#define NS 256
#define ND 128
#define MAXT 12          // max 32-row tiles per doc (sum ceil(c_m/32) <= 11)
#define PERMSTRIDE 384   // MAXT*32

typedef __bf16 bf16x8 __attribute__((ext_vector_type(8)));
typedef float f32x16 __attribute__((ext_vector_type(16)));

// workspace layout (bytes)
#define OFF_TILEMOD 0u          // 64*12*4 = 3072
#define OFF_TCOUNT  4096u       // 64*4
#define OFF_DFRAG   16384u      // 64*12*8*64*16 = 6291456
#define OFF_QFRAG   6307840u    // 64*8*64*16    = 524288
#define OFF_SIMOUT  6832128u    // 64*64*5*4     = 81920
#define OFF_RED     6914048u    // bpcnt[32] @ +0, gcnt @ +128, gacc @ +192

// ---------------------------------------------------------------------------
// Kernel 1 (fused prep + fragment swizzle), pad-to-32 for 32x32x16 MFMA.
// Blocks 0..63: doc c — modality partition (stable, pad segments to x32 by
//   duplicating the segment's first token; max-invariant), then fp32->bf16
//   swizzle into MFMA A-operand layout. Block 0 zeroes the loss reduction.
// Blocks 64..127: query b — B-operand layout.
// ---------------------------------------------------------------------------
__global__ __launch_bounds__(256) void
prep_frag_kernel(const float* __restrict__ qemb, const float* __restrict__ demb,
                 const int* __restrict__ mod,
                 __bf16* __restrict__ qfrag, __bf16* __restrict__ dfrag,
                 int* __restrict__ tilemod_g, int* __restrict__ tcount_g,
                 int* __restrict__ red) {
    int blk = blockIdx.x;
    int tid = threadIdx.x;
    int lane = tid & 63, wv = tid >> 6;
    int li32 = lane & 31, kh = lane >> 5;

    if (blk == 0 && tid < 34) {
        if (tid < 32) red[tid] = 0;                 // bpcnt
        else if (tid == 32) red[32] = 0;            // gcnt
        else ((float*)red)[48] = 0.f;               // gacc @ +192 bytes
    }

    if (blk >= NB) {
        // ---- query fragments: lane holds q col li32, k = kc*16 + kh*8 + j ----
        int b = blk - NB;
#pragma unroll
        for (int i = 0; i < 2; ++i) {
            int kc = wv * 2 + i;               // 0..7
            int k0 = kc * 16 + kh * 8;
            const float* src = qemb + ((size_t)b * NQ + li32) * ND + k0;
            float4 a = *(const float4*)src;
            float4 bq = *(const float4*)(src + 4);
            bf16x8 o;
            o[0] = (__bf16)a.x;  o[1] = (__bf16)a.y;  o[2] = (__bf16)a.z;  o[3] = (__bf16)a.w;
            o[4] = (__bf16)bq.x; o[5] = (__bf16)bq.y; o[6] = (__bf16)bq.z; o[7] = (__bf16)bq.w;
            *(bf16x8*)(qfrag + (((size_t)b * 8 + kc) * 64 + lane) * 8) = o;
        }
        return;
    }

    // ---- doc partition + fragments ----
    int c = blk;
    __shared__ int smod[NS];
    __shared__ int sperm[PERMSTRIDE];
    __shared__ int counts[5], firsts[5], offs[5], padded[5];
    __shared__ int stilemod[MAXT];
    __shared__ int sT;

    if (tid < 5) { counts[tid] = 0; firsts[tid] = NS; }
    __syncthreads();
    int m_tok = mod[c * NS + tid];
    smod[tid] = m_tok;
    if (m_tok) { atomicAdd(&counts[m_tok], 1); atomicMin(&firsts[m_tok], tid); }
    __syncthreads();
    if (tid == 0) {
        int pos = 0;
        for (int m = 1; m <= 4; ++m) {
            offs[m] = pos;
            int p = (counts[m] + 31) & ~31;
            padded[m] = p;
            for (int t = pos >> 5; t < (pos + p) >> 5; ++t) stilemod[t] = m;
            pos += p;
        }
        sT = pos >> 5;
        tcount_g[c] = pos >> 5;
    }
    __syncthreads();
    // stable rank within modality, scatter into sperm
    if (m_tok) {
        int rank = 0;
        for (int s = 0; s < tid; ++s) rank += (smod[s] == m_tok);
        sperm[offs[m_tok] + rank] = tid;
    }
    // pad slots get the segment's first token (max-invariant duplicate)
    if (tid < 4) {
        int m = tid + 1;
        for (int p = counts[m]; p < padded[m]; ++p) sperm[offs[m] + p] = firsts[m];
    }
    __syncthreads();
    int T = sT;
    if (tid < T) tilemod_g[c * MAXT + tid] = stilemod[tid];

    // fragment swizzle: lane holds doc row li32 of tile t, k = kc*16+kh*8+j
    for (int kc = wv; kc < 8; kc += 4) {
        int k0 = kc * 16 + kh * 8;
        for (int t = 0; t < T; ++t) {
            int srow = sperm[t * 32 + li32];
            const float* src = demb + ((size_t)c * NS + srow) * ND + k0;
            float4 a = *(const float4*)src;
            float4 bq = *(const float4*)(src + 4);
            bf16x8 o;
            o[0] = (__bf16)a.x;  o[1] = (__bf16)a.y;  o[2] = (__bf16)a.z;  o[3] = (__bf16)a.w;
            o[4] = (__bf16)bq.x; o[5] = (__bf16)bq.y; o[6] = (__bf16)bq.z; o[7] = (__bf16)bq.w;
            *(bf16x8*)(dfrag + (((size_t)(c * MAXT + t) * 8 + kc) * 64 + lane) * 8) = o;
        }
    }
}

// ---------------------------------------------------------------------------
// Kernel 2: main (32x32x16 MFMA, unchanged hot loop — absmax 0.0 verified)
// + fence-free fused loss tail:
//  * simout written via agent-scope atomic stores (coherence-point writes,
//    no dirty L2, no wbl2/inv anywhere — R3 lesson).
//  * __syncthreads drains vmem before the per-bp counter RMW (release-free
//    ordering); 64th block of each b-pair computes 2 rows' logsumexp reading
//    simout via agent-scope atomic loads (stale-L2-proof).
//  * row losses -> fp32 atomicAdd + counter (R7-validated), vmcnt-drained.
// ---------------------------------------------------------------------------
__global__ __launch_bounds__(256) void
main_kernel(const __bf16* __restrict__ dfrag, const __bf16* __restrict__ qfrag,
            const int* __restrict__ tilemod, const int* __restrict__ tcount,
            const int* __restrict__ qmask, const int* __restrict__ qtypes,
            float* __restrict__ simout, int* __restrict__ red,
            float* __restrict__ out) {
    int blk = blockIdx.x;
    int c  = (blk & 7) * 8 + (blk >> 8);
    int bp = (blk >> 3) & 31;
    int b0 = bp * 2;
    int tid = threadIdx.x;
    int lane = tid & 63, wv = tid >> 6;

    bf16x8 bfrag[2][8];
#pragma unroll
    for (int bi = 0; bi < 2; ++bi)
#pragma unroll
        for (int kc = 0; kc < 8; ++kc)
            bfrag[bi][kc] = *(const bf16x8*)(qfrag + (((size_t)(b0 + bi) * 8 + kc) * 64 + lane) * 8);

    float vmax[2][4];
#pragma unroll
    for (int bi = 0; bi < 2; ++bi)
#pragma unroll
        for (int m = 0; m < 4; ++m) vmax[bi][m] = -1e30f;

    int T = tcount[c];
    for (int t = wv; t < T; t += 4) {
        bf16x8 af[8];
#pragma unroll
        for (int kc = 0; kc < 8; ++kc)
            af[kc] = *(const bf16x8*)(dfrag + (((size_t)(c * MAXT + t) * 8 + kc) * 64 + lane) * 8);
        int tm = tilemod[c * MAXT + t];   // wave-uniform
#pragma unroll
        for (int bi = 0; bi < 2; ++bi) {
            f32x16 acc = {0.f,0.f,0.f,0.f,0.f,0.f,0.f,0.f,0.f,0.f,0.f,0.f,0.f,0.f,0.f,0.f};
#pragma unroll
            for (int kc = 0; kc < 8; ++kc)
                acc = __builtin_amdgcn_mfma_f32_32x32x16_bf16(af[kc], bfrag[bi][kc], acc, 0, 0, 0);
            float v = acc[0];
#pragma unroll
            for (int r = 1; r < 16; ++r) v = fmaxf(v, acc[r]);
            v = fmaxf(v, __shfl_xor(v, 32, 64));
            switch (tm) {
            case 1:  vmax[bi][0] = fmaxf(vmax[bi][0], v); break;
            case 2:  vmax[bi][1] = fmaxf(vmax[bi][1], v); break;
            case 3:  vmax[bi][2] = fmaxf(vmax[bi][2], v); break;
            default: vmax[bi][3] = fmaxf(vmax[bi][3], v); break;
            }
        }
    }

    __shared__ float lv[4][2][4][32];   // 4 KB
    if (lane < 32) {
#pragma unroll
        for (int bi = 0; bi < 2; ++bi)
#pragma unroll
            for (int m = 0; m < 4; ++m) lv[wv][bi][m][lane] = vmax[bi][m];
    }
    __syncthreads();
    __shared__ float l2s[2][4][32];     // 1 KB
    {
        int bi = tid >> 7, m = (tid >> 5) & 3, q = tid & 31;
        float v = fmaxf(fmaxf(lv[0][bi][m][q], lv[1][bi][m][q]),
                        fmaxf(lv[2][bi][m][q], lv[3][bi][m][q]));
        l2s[bi][m][q] = v;
    }
    __syncthreads();
    if (tid < 64) {
        int bi = tid >> 5, q = tid & 31;
        float m1 = l2s[bi][0][q], m2 = l2s[bi][1][q];
        float m3 = l2s[bi][2][q], m4 = l2s[bi][3][q];
        int b = b0 + bi;
        float agg = fmaxf(fmaxf(m1, m2), fmaxf(m3, m4));
        float s0 = (qmask[b * NQ + q] != 0) ? agg : 0.f;
        float s1 = m1, s2 = m2, s3 = m3, s4 = m4;
#pragma unroll
        for (int off = 16; off >= 1; off >>= 1) {
            s0 += __shfl_xor(s0, off, 64);
            s1 += __shfl_xor(s1, off, 64);
            s2 += __shfl_xor(s2, off, 64);
            s3 += __shfl_xor(s3, off, 64);
            s4 += __shfl_xor(s4, off, 64);
        }
        if (q == 0) {
            float* o = simout + ((size_t)b * NB + c) * 5;   // UNNORMALIZED sums
            __hip_atomic_store(&o[0], s0, __ATOMIC_RELAXED, __HIP_MEMORY_SCOPE_AGENT);
            __hip_atomic_store(&o[1], s1, __ATOMIC_RELAXED, __HIP_MEMORY_SCOPE_AGENT);
            __hip_atomic_store(&o[2], s2, __ATOMIC_RELAXED, __HIP_MEMORY_SCOPE_AGENT);
            __hip_atomic_store(&o[3], s3, __ATOMIC_RELAXED, __HIP_MEMORY_SCOPE_AGENT);
            __hip_atomic_store(&o[4], s4, __ATOMIC_RELAXED, __HIP_MEMORY_SCOPE_AGENT);
        }
    }

    // ---- fused loss tail: 64th block of this b-pair computes rows b0,b0+1 ----
    __shared__ int swin;
    __syncthreads();                       // drains vmcnt(0): stores at coherence pt
    if (tid == 0) swin = (atomicAdd(&red[bp], 1) == 63);
    __syncthreads();
    if (!swin) return;

    __shared__ float sv[320];
    __shared__ float wred[4];
    __shared__ int scnt;
    float lr_sum = 0.f;
#pragma unroll
    for (int bi = 0; bi < 2; ++bi) {
        int r = b0 + bi;
        for (int i = tid; i < 320; i += 256)
            sv[i] = __hip_atomic_load(&simout[(size_t)r * 320 + i],
                                      __ATOMIC_RELAXED, __HIP_MEMORY_SCOPE_AGENT);
        if (wv == 0) {
            int on = (lane < NQ) ? (qmask[r * NQ + lane] != 0) : 0;
            unsigned long long bal = __ballot(on);
            if (lane == 0) scnt = __popcll(bal);
        }
        __syncthreads();
        int cq = scnt;
        float scale = 1.0f / (TAU_F * (float)(cq > 0 ? cq : 1));
        int skip = r * 5;
        float mx = -1e30f;
        for (int i = tid; i < 320; i += 256)
            if (i != skip) mx = fmaxf(mx, sv[i] * scale);
#pragma unroll
        for (int off = 32; off >= 1; off >>= 1) mx = fmaxf(mx, __shfl_xor(mx, off, 64));
        if (lane == 0) wred[wv] = mx;
        __syncthreads();
        mx = fmaxf(fmaxf(wred[0], wred[1]), fmaxf(wred[2], wred[3]));
        float sum = 0.f;
        for (int i = tid; i < 320; i += 256)
            if (i != skip) sum += expf(sv[i] * scale - mx);
#pragma unroll
        for (int off = 32; off >= 1; off >>= 1) sum += __shfl_xor(sum, off, 64);
        __syncthreads();
        if (lane == 0) wred[wv] = sum;
        __syncthreads();
        if (tid == 0) {
            float tot = wred[0] + wred[1] + wred[2] + wred[3];
            float pos = sv[r * 5 + qtypes[r]] * scale;
            lr_sum += (logf(tot) + mx - pos) * (1.0f / NB);
        }
        __syncthreads();
    }
    if (tid == 0) {
        float* gacc = (float*)red + 48;
        float ret = atomicAdd(gacc, lr_sum);             // device-coherent RMW
        asm volatile("s_waitcnt vmcnt(0)" ::: "memory"); // acc add globally done
        int bump = 1 + (ret > 1e37f ? 1 : 0);            // data-dep belt+braces
        int old = atomicAdd(&red[32], bump);
        if (old == 31) {
            float v = atomicAdd(gacc, 0.f);              // coherent read-back
            out[0] = v;
        }
    }
}

// ---------------------------------------------------------------------------
extern "C" void kernel_launch(void* const* d_in, const int* in_sizes, int n_in,
                              void* d_out, int out_size, void* d_ws, size_t ws_size,
                              hipStream_t stream) {
    const float* qemb   = (const float*)d_in[0];
    const float* demb   = (const float*)d_in[1];
    const int*   mod    = (const int*)d_in[2];
    const int*   qtypes = (const int*)d_in[3];
    const int*   qmask  = (const int*)d_in[4];

    char* ws = (char*)d_ws;
    int*    tilemod = (int*)(ws + OFF_TILEMOD);
    int*    tcount  = (int*)(ws + OFF_TCOUNT);
    __bf16* dfrag   = (__bf16*)(ws + OFF_DFRAG);
    __bf16* qfrag   = (__bf16*)(ws + OFF_QFRAG);
    float*  simout  = (float*)(ws + OFF_SIMOUT);
    int*    red     = (int*)(ws + OFF_RED);

    prep_frag_kernel<<<2 * NB, 256, 0, stream>>>(qemb, demb, mod, qfrag, dfrag,
                                                 tilemod, tcount, red);
    main_kernel<<<2048, 256, 0, stream>>>(dfrag, qfrag, tilemod, tcount, qmask,
                                          qtypes, simout, red, (float*)d_out);
}

// Round 9
// 90.655 us; speedup vs baseline: 1.1150x; 1.1150x over previous
//
#include <hip/hip_runtime.h>
#include <math.h>

#define TAU_F 0.02f
#define NB 64
#define NQ 32
#define NS 256
#define ND 128
#define MAXT 12          // max 32-row tiles per doc (sum ceil(c_m/32)*32 <= 379)
#define PERMSTRIDE 384   // MAXT*32

typedef __bf16 bf16x8 __attribute__((ext_vector_type(8)));
typedef float f32x16 __attribute__((ext_vector_type(16)));

// workspace layout (bytes)
#define OFF_TILEMOD 0u          // 64*12*4 = 3072
#define OFF_TCOUNT  4096u       // 64*4
#define OFF_DFRAG   16384u      // 64*12*8*64*16 = 6291456
#define OFF_QFRAG   6307840u    // 64*8*64*16    = 524288
#define OFF_SIMOUT  6832128u    // 64*64*5*4     = 81920
#define OFF_RED     6914048u    // counter @ +0, acc(float) @ +64 bytes

// ---------------------------------------------------------------------------
// Kernel 1 (fused prep + fragment swizzle), pad-to-32 for 32x32x16 MFMA.
// Unchanged from R7 (absmax 0.0 verified).
// ---------------------------------------------------------------------------
__global__ __launch_bounds__(256) void
prep_frag_kernel(const float* __restrict__ qemb, const float* __restrict__ demb,
                 const int* __restrict__ mod,
                 __bf16* __restrict__ qfrag, __bf16* __restrict__ dfrag,
                 int* __restrict__ tilemod_g, int* __restrict__ tcount_g,
                 int* __restrict__ red) {
    int blk = blockIdx.x;
    int tid = threadIdx.x;
    int lane = tid & 63, wv = tid >> 6;
    int li32 = lane & 31, kh = lane >> 5;

    if (blk == 0 && tid == 0) { red[0] = 0; ((float*)red)[16] = 0.f; }

    if (blk >= NB) {
        // ---- query fragments: lane holds q col li32, k = kc*16 + kh*8 + j ----
        int b = blk - NB;
#pragma unroll
        for (int i = 0; i < 2; ++i) {
            int kc = wv * 2 + i;               // 0..7
            int k0 = kc * 16 + kh * 8;
            const float* src = qemb + ((size_t)b * NQ + li32) * ND + k0;
            float4 a = *(const float4*)src;
            float4 bq = *(const float4*)(src + 4);
            bf16x8 o;
            o[0] = (__bf16)a.x;  o[1] = (__bf16)a.y;  o[2] = (__bf16)a.z;  o[3] = (__bf16)a.w;
            o[4] = (__bf16)bq.x; o[5] = (__bf16)bq.y; o[6] = (__bf16)bq.z; o[7] = (__bf16)bq.w;
            *(bf16x8*)(qfrag + (((size_t)b * 8 + kc) * 64 + lane) * 8) = o;
        }
        return;
    }

    // ---- doc partition + fragments ----
    int c = blk;
    __shared__ int smod[NS];
    __shared__ int sperm[PERMSTRIDE];
    __shared__ int counts[5], firsts[5], offs[5], padded[5];
    __shared__ int stilemod[MAXT];
    __shared__ int sT;

    if (tid < 5) { counts[tid] = 0; firsts[tid] = NS; }
    __syncthreads();
    int m_tok = mod[c * NS + tid];
    smod[tid] = m_tok;
    if (m_tok) { atomicAdd(&counts[m_tok], 1); atomicMin(&firsts[m_tok], tid); }
    __syncthreads();
    if (tid == 0) {
        int pos = 0;
        for (int m = 1; m <= 4; ++m) {
            offs[m] = pos;
            int p = (counts[m] + 31) & ~31;
            padded[m] = p;
            for (int t = pos >> 5; t < (pos + p) >> 5; ++t) stilemod[t] = m;
            pos += p;
        }
        sT = pos >> 5;
        tcount_g[c] = pos >> 5;
    }
    __syncthreads();
    // stable rank within modality, scatter into sperm
    if (m_tok) {
        int rank = 0;
        for (int s = 0; s < tid; ++s) rank += (smod[s] == m_tok);
        sperm[offs[m_tok] + rank] = tid;
    }
    // pad slots get the segment's first token (max-invariant duplicate)
    if (tid < 4) {
        int m = tid + 1;
        for (int p = counts[m]; p < padded[m]; ++p) sperm[offs[m] + p] = firsts[m];
    }
    __syncthreads();
    int T = sT;
    if (tid < T) tilemod_g[c * MAXT + tid] = stilemod[tid];

    // fragment swizzle: lane holds doc row li32 of tile t, k = kc*16+kh*8+j
    for (int kc = wv; kc < 8; kc += 4) {
        int k0 = kc * 16 + kh * 8;
        for (int t = 0; t < T; ++t) {
            int srow = sperm[t * 32 + li32];
            const float* src = demb + ((size_t)c * NS + srow) * ND + k0;
            float4 a = *(const float4*)src;
            float4 bq = *(const float4*)(src + 4);
            bf16x8 o;
            o[0] = (__bf16)a.x;  o[1] = (__bf16)a.y;  o[2] = (__bf16)a.z;  o[3] = (__bf16)a.w;
            o[4] = (__bf16)bq.x; o[5] = (__bf16)bq.y; o[6] = (__bf16)bq.z; o[7] = (__bf16)bq.w;
            *(bf16x8*)(dfrag + (((size_t)(c * MAXT + t) * 8 + kc) * 64 + lane) * 8) = o;
        }
    }
}

// ---------------------------------------------------------------------------
// Kernel 2: main, restructured (R9). 512 blocks = 64 docs x 8 query-batches;
// all 8 blocks of a doc on one XCD. Each WAVE owns 2 b's end-to-end: its own
// bfrag (no redundant loads), all T tiles (176 MFMAs/wave), private epilogue
// (no cross-wave reduction). Doc tiles double-buffered through LDS with a
// global->VGPR prefetch software pipeline (one barrier per tile).
// ---------------------------------------------------------------------------
__global__ __launch_bounds__(256, 2) void
main_kernel(const __bf16* __restrict__ dfrag, const __bf16* __restrict__ qfrag,
            const int* __restrict__ tilemod, const int* __restrict__ tcount,
            const int* __restrict__ qmask, float* __restrict__ simout) {
    int blk = blockIdx.x;              // 0..511
    int xcd = blk & 7;
    int idx = blk >> 3;                // 0..63
    int c   = xcd * 8 + (idx & 7);     // doc; 8 blocks per doc share an XCD
    int bq  = idx >> 3;                // 0..7 query-batch
    int tid = threadIdx.x;
    int lane = tid & 63, wv = tid >> 6;
    int b0 = bq * 8 + wv * 2;          // this wave's 2 b's

    // per-wave query fragments (distinct per wave)
    bf16x8 bfrag[2][8];
#pragma unroll
    for (int bi = 0; bi < 2; ++bi)
#pragma unroll
        for (int kc = 0; kc < 8; ++kc)
            bfrag[bi][kc] = *(const bf16x8*)(qfrag + (((size_t)(b0 + bi) * 8 + kc) * 64 + lane) * 8);

    __shared__ __bf16 sbuf[2][8 * 64 * 8];   // 2 x 8 KB tile buffers

    int T = tcount[c];
    const __bf16* dbase = dfrag + (size_t)c * MAXT * 4096;

    // stage tile 0 (coalesced: 256 threads x 2 x 16B)
    {
        const __bf16* src = dbase;
        *(bf16x8*)&sbuf[0][(size_t)tid * 8]          = *(const bf16x8*)(src + (size_t)tid * 8);
        *(bf16x8*)&sbuf[0][2048 + (size_t)tid * 8]   = *(const bf16x8*)(src + 2048 + (size_t)tid * 8);
    }
    __syncthreads();

    float vmax[2][4];
#pragma unroll
    for (int bi = 0; bi < 2; ++bi)
#pragma unroll
        for (int m = 0; m < 4; ++m) vmax[bi][m] = -1e30f;

    int cur = 0;
    for (int t = 0; t < T; ++t) {
        // prefetch next tile into VGPRs (latency hidden behind compute)
        bf16x8 p0, p1;
        bool pf = (t + 1 < T);
        if (pf) {
            const __bf16* src = dbase + (size_t)(t + 1) * 4096;
            p0 = *(const bf16x8*)(src + (size_t)tid * 8);
            p1 = *(const bf16x8*)(src + 2048 + (size_t)tid * 8);
        }

        int tm = tilemod[c * MAXT + t];   // wave-uniform
        f32x16 acc0 = {0.f,0.f,0.f,0.f,0.f,0.f,0.f,0.f,0.f,0.f,0.f,0.f,0.f,0.f,0.f,0.f};
        f32x16 acc1 = acc0;
#pragma unroll
        for (int kc = 0; kc < 8; ++kc) {
            bf16x8 af = *(const bf16x8*)&sbuf[cur][(kc * 64 + lane) * 8];
            acc0 = __builtin_amdgcn_mfma_f32_32x32x16_bf16(af, bfrag[0][kc], acc0, 0, 0, 0);
            acc1 = __builtin_amdgcn_mfma_f32_32x32x16_bf16(af, bfrag[1][kc], acc1, 0, 0, 0);
        }
        float v0 = acc0[0], v1 = acc1[0];
#pragma unroll
        for (int r = 1; r < 16; ++r) { v0 = fmaxf(v0, acc0[r]); v1 = fmaxf(v1, acc1[r]); }
        v0 = fmaxf(v0, __shfl_xor(v0, 32, 64));
        v1 = fmaxf(v1, __shfl_xor(v1, 32, 64));
        switch (tm) {
        case 1:  vmax[0][0] = fmaxf(vmax[0][0], v0); vmax[1][0] = fmaxf(vmax[1][0], v1); break;
        case 2:  vmax[0][1] = fmaxf(vmax[0][1], v0); vmax[1][1] = fmaxf(vmax[1][1], v1); break;
        case 3:  vmax[0][2] = fmaxf(vmax[0][2], v0); vmax[1][2] = fmaxf(vmax[1][2], v1); break;
        default: vmax[0][3] = fmaxf(vmax[0][3], v0); vmax[1][3] = fmaxf(vmax[1][3], v1); break;
        }

        if (pf) {
            *(bf16x8*)&sbuf[cur ^ 1][(size_t)tid * 8]        = p0;
            *(bf16x8*)&sbuf[cur ^ 1][2048 + (size_t)tid * 8] = p1;
        }
        __syncthreads();
        cur ^= 1;
    }

    // per-wave epilogue: no cross-wave reduction needed (wave owns its 2 b's)
    int q = lane & 31;
#pragma unroll
    for (int bi = 0; bi < 2; ++bi) {
        int b = b0 + bi;
        float m1 = vmax[bi][0], m2 = vmax[bi][1], m3 = vmax[bi][2], m4 = vmax[bi][3];
        float agg = fmaxf(fmaxf(m1, m2), fmaxf(m3, m4));
        float s0 = (qmask[b * NQ + q] != 0) ? agg : 0.f;
        float s1 = m1, s2 = m2, s3 = m3, s4 = m4;
#pragma unroll
        for (int off = 16; off >= 1; off >>= 1) {   // fold within 32-lane half
            s0 += __shfl_xor(s0, off, 64);
            s1 += __shfl_xor(s1, off, 64);
            s2 += __shfl_xor(s2, off, 64);
            s3 += __shfl_xor(s3, off, 64);
            s4 += __shfl_xor(s4, off, 64);
        }
        if (lane == 0) {
            float* o = simout + ((size_t)b * NB + c) * 5;   // UNNORMALIZED sums
            o[0] = s0; o[1] = s1; o[2] = s2; o[3] = s3; o[4] = s4;
        }
    }
}

// ---------------------------------------------------------------------------
// Kernel 3: loss, 64 blocks (one per row) — unchanged from R7 (validated).
// ---------------------------------------------------------------------------
__global__ __launch_bounds__(256) void
loss_kernel(const float* __restrict__ simout, const int* __restrict__ qtypes,
            const int* __restrict__ qmask, int* __restrict__ red,
            float* __restrict__ out) {
    int r = blockIdx.x;
    int tid = threadIdx.x;
    int lane = tid & 63, wv = tid >> 6;

    __shared__ float sv[320];
    for (int i = tid; i < 320; i += 256) sv[i] = simout[(size_t)r * 320 + i];

    __shared__ int scnt;
    if (wv == 0) {
        int on = (lane < NQ) ? (qmask[r * NQ + lane] != 0) : 0;
        unsigned long long bal = __ballot(on);
        if (lane == 0) scnt = __popcll(bal);
    }
    __syncthreads();
    int cq = scnt;
    float scale = 1.0f / (TAU_F * (float)(cq > 0 ? cq : 1));
    int skip = r * 5;                      // the agg-sim diagonal slot

    __shared__ float wred[4];
    float mx = -1e30f;
    for (int i = tid; i < 320; i += 256)
        if (i != skip) mx = fmaxf(mx, sv[i] * scale);
#pragma unroll
    for (int off = 32; off >= 1; off >>= 1) mx = fmaxf(mx, __shfl_xor(mx, off, 64));
    if (lane == 0) wred[wv] = mx;
    __syncthreads();
    mx = fmaxf(fmaxf(wred[0], wred[1]), fmaxf(wred[2], wred[3]));

    float sum = 0.f;
    for (int i = tid; i < 320; i += 256)
        if (i != skip) sum += expf(sv[i] * scale - mx);
#pragma unroll
    for (int off = 32; off >= 1; off >>= 1) sum += __shfl_xor(sum, off, 64);
    __syncthreads();
    if (lane == 0) wred[wv] = sum;
    __syncthreads();

    if (tid == 0) {
        float tot = wred[0] + wred[1] + wred[2] + wred[3];
        float pos = sv[r * 5 + qtypes[r]] * scale;
        float lr = (logf(tot) + mx - pos) * (1.0f / NB);
        float* acc = (float*)red + 16;
        float ret = atomicAdd(acc, lr);                  // device-coherent
        int bump = 1 + (ret > 1e37f ? 1 : 0);            // data-dep: wait ret
        int old = atomicAdd(red, bump);
        if (old == NB - 1) {
            float v = atomicAdd(acc, 0.f);               // coherent read-back
            out[0] = v;
        }
    }
}

// ---------------------------------------------------------------------------
extern "C" void kernel_launch(void* const* d_in, const int* in_sizes, int n_in,
                              void* d_out, int out_size, void* d_ws, size_t ws_size,
                              hipStream_t stream) {
    const float* qemb   = (const float*)d_in[0];
    const float* demb   = (const float*)d_in[1];
    const int*   mod    = (const int*)d_in[2];
    const int*   qtypes = (const int*)d_in[3];
    const int*   qmask  = (const int*)d_in[4];

    char* ws = (char*)d_ws;
    int*    tilemod = (int*)(ws + OFF_TILEMOD);
    int*    tcount  = (int*)(ws + OFF_TCOUNT);
    __bf16* dfrag   = (__bf16*)(ws + OFF_DFRAG);
    __bf16* qfrag   = (__bf16*)(ws + OFF_QFRAG);
    float*  simout  = (float*)(ws + OFF_SIMOUT);
    int*    red     = (int*)(ws + OFF_RED);

    prep_frag_kernel<<<2 * NB, 256, 0, stream>>>(qemb, demb, mod, qfrag, dfrag,
                                                 tilemod, tcount, red);
    main_kernel<<<512, 256, 0, stream>>>(dfrag, qfrag, tilemod, tcount, qmask, simout);
    loss_kernel<<<NB, 256, 0, stream>>>(simout, qtypes, qmask, red, (float*)d_out);
}